// Round 6
// baseline (679.828 us; speedup 1.0000x reference)
//
#include <hip/hip_runtime.h>
#include <hip/hip_bf16.h>

typedef __attribute__((ext_vector_type(8))) short short8;
typedef __attribute__((ext_vector_type(4))) float f32x4;
typedef __attribute__((ext_vector_type(16))) float f32x16;
typedef __attribute__((ext_vector_type(4))) unsigned int u32x4;

#define NB 8
#define NC 256
#define NNN 4096
#define L2E 1.44269504088896f

__device__ __forceinline__ ushort f2bf(float f) {
  __hip_bfloat16 h = __float2bfloat16(f);
  return *reinterpret_cast<ushort*>(&h);
}
__device__ __forceinline__ unsigned pack2(float a, float b) {
  return (unsigned)f2bf(a) | ((unsigned)f2bf(b) << 16);
}
__device__ __forceinline__ void gload16(const void* g, void* l) {
  __builtin_amdgcn_global_load_lds(
      (const __attribute__((address_space(1))) void*)g,
      (__attribute__((address_space(3))) void*)l, 16, 0, 0);
}

// fTs[b][n][c ^ ((n&7)<<3)] = bf16(x[b][c][n])   (chunk-swizzled rows, 512B)
__global__ __launch_bounds__(256) void prep_T(const float* __restrict__ x,
                                              ushort* __restrict__ fTs) {
  __shared__ float tile[32][33];
  const int tx = threadIdx.x, ty = threadIdx.y;
  const int n0 = blockIdx.x * 32, c0 = blockIdx.y * 32, b = blockIdx.z;
#pragma unroll
  for (int k = 0; k < 4; ++k) {
    tile[ty + 8 * k][tx] =
        x[((size_t)(b * NC + c0 + ty + 8 * k)) * NNN + n0 + tx];
  }
  __syncthreads();
#pragma unroll
  for (int k = 0; k < 4; ++k) {
    const int n = n0 + ty + 8 * k;
    const int c = c0 + tx;
    fTs[(size_t)(b * NNN + n) * NC + (c ^ ((n & 7) << 3))] =
        f2bf(tile[tx][ty + 8 * k]);
  }
}

// fVs[b][c][64t + (mm ^ ((c&7)<<3))] = bf16(x[b][c][64t+mm])
__global__ __launch_bounds__(256) void prep_V(const float* __restrict__ x,
                                              ushort* __restrict__ fVs) {
  const size_t ci = (size_t)blockIdx.x * 256 + threadIdx.x;  // 1M chunks
  const int p = (int)(ci & 511);
  const int c = (int)((ci >> 9) & 255);
  const int b = (int)(ci >> 17);
  const int lp = (p & ~7) | ((p & 7) ^ (c & 7));  // logical chunk
  const float* src = x + ((size_t)(b * NC + c)) * NNN + lp * 8;
  f32x4 a0 = *(const f32x4*)src;
  f32x4 a1 = *(const f32x4*)(src + 4);
  short8 w;
  w[0] = (short)f2bf(a0[0]); w[1] = (short)f2bf(a0[1]);
  w[2] = (short)f2bf(a0[2]); w[3] = (short)f2bf(a0[3]);
  w[4] = (short)f2bf(a1[0]); w[5] = (short)f2bf(a1[1]);
  w[6] = (short)f2bf(a1[2]); w[7] = (short)f2bf(a1[3]);
  *(short8*)(fVs + ((size_t)(b * NC + c)) * NNN + p * 8) = w;
}

// Flash attention, 32x32x16 MFMA, swapped QK^T, O^T (n per-lane) accumulation.
// 256 threads = 4 waves, each 32 query cols, full 64-m tiles.
// SPLIT=1: 512 blocks (2 key-halves, 32 tiles each), 64KB LDS -> 2 blocks/CU;
//          writes unnormalized O + (m,l) partials, combine_kernel merges.
// SPLIT=0: 256 blocks, 64 tiles, writes out directly (ws fallback).
template <int SPLIT>
__global__ __launch_bounds__(256, 2) void attn_kernel(
    const float* __restrict__ x, const ushort* __restrict__ fTs,
    const ushort* __restrict__ fVs, const float* __restrict__ gamma,
    float* __restrict__ out, float* __restrict__ OH, float* __restrict__ mS,
    float* __restrict__ lS) {
  __shared__ __align__(16) char smem[65536];  // K 32KB @0, V 32KB @32768

  const int tid = threadIdx.x;
  const int w = tid >> 6;
  const int l = tid & 63;
  const int l31 = l & 31;
  const int h = l >> 5;
  const int bid = blockIdx.x;
  const int b = bid & 7;                    // batch -> XCD
  const int nt = (bid >> 3) & 31;           // n-tile (128 rows)
  const int half = SPLIT ? (bid >> 8) : 0;  // key half
  const int n0w = nt * 128 + w * 32;        // this wave's 32 query cols
  const int T = SPLIT ? 32 : 64;
  const int tBase = SPLIT ? half * 32 : 0;

  const char* fTb = (const char*)(fTs + (size_t)b * NNN * NC);
  const char* fVb = (const char*)(fVs + (size_t)b * NNN * NC);

  // Q fragments (B operand): col n = l31 -> row n0w+l31; k = kc*16+8h+j
  short8 q[16];
  {
    const char* qrow = fTb + (size_t)(n0w + l31) * 512;
    const int sw = (l31 & 7) << 4;
#pragma unroll
    for (int kc = 0; kc < 16; ++kc)
      q[kc] = *(const short8*)(qrow + ((kc * 32 + 16 * h) ^ sw));
  }

  // O^T accumulator: rows c = cf*32 + (r&3)+8*(r>>2)+4h, cols n = l31
  f32x16 o[8];
#pragma unroll
  for (int cf = 0; cf < 8; ++cf)
#pragma unroll
    for (int r = 0; r < 16; ++r) o[cf][r] = 0.f;
  float m_run = -3.0e38f, l_run = 0.f;

  // DMA staging sources (per-lane), dest linear per wave (round-4 verified)
  const char* gK0 = fTb + (size_t)(w * 16 + (l >> 5)) * 512 + (l & 31) * 16;
  const char* gV0 = fVb + (size_t)(w * 64 + (l >> 3)) * 8192 + (l & 7) * 16;

#define STAGE(tt)                                                      \
  {                                                                    \
    const size_t kOff = (size_t)(tt) * 32768;                          \
    const size_t vOff = (size_t)(tt) * 128;                            \
    _Pragma("unroll") for (int i = 0; i < 8; ++i)                      \
        gload16(gK0 + kOff + i * 1024, smem + w * 8192 + i * 1024);    \
    _Pragma("unroll") for (int i = 0; i < 8; ++i)                      \
        gload16(gV0 + vOff + (size_t)i * 65536,                        \
                smem + 32768 + w * 8192 + i * 1024);                   \
  }

  STAGE(tBase);
  __syncthreads();

  const int ksw = (l31 & 7) << 4;

  for (int t = 0; t < T; ++t) {
    // ---- S^T = K * Q^T : two independent 16-chains (m 0-31, 32-63) ----
    f32x16 s0, s1;
#pragma unroll
    for (int r = 0; r < 16; ++r) { s0[r] = 0.f; s1[r] = 0.f; }
    __builtin_amdgcn_s_setprio(1);
#pragma unroll
    for (int kc = 0; kc < 16; ++kc) {
      const int bb = (kc * 32 + 16 * h) ^ ksw;
      short8 ka0 = *(const short8*)(smem + l31 * 512 + bb);
      short8 ka1 = *(const short8*)(smem + (32 + l31) * 512 + bb);
      s0 = __builtin_amdgcn_mfma_f32_32x32x16_bf16(ka0, q[kc], s0, 0, 0, 0);
      s1 = __builtin_amdgcn_mfma_f32_32x32x16_bf16(ka1, q[kc], s1, 0, 0, 0);
    }
    __builtin_amdgcn_s_setprio(0);

    // ---- online softmax; lane owns col n = l31 (stats lane-local) ----
    float tm = s0[0];
#pragma unroll
    for (int r = 1; r < 16; ++r) tm = fmaxf(tm, s0[r]);
#pragma unroll
    for (int r = 0; r < 16; ++r) tm = fmaxf(tm, s1[r]);
    tm = fmaxf(tm, __shfl_xor(tm, 32));

    if (__any(tm > m_run + 8.f)) {  // T13 defer-max
      const float mnew = fmaxf(m_run, tm);
      const float alpha = exp2f((m_run - mnew) * L2E);
      m_run = mnew;
      l_run *= alpha;
#pragma unroll
      for (int cf = 0; cf < 8; ++cf)
#pragma unroll
        for (int r = 0; r < 16; ++r) o[cf][r] *= alpha;  // lane-local
    }

    float rsum = 0.f;
#pragma unroll
    for (int r = 0; r < 16; ++r) {
      const float pv = exp2f((s0[r] - m_run) * L2E); s0[r] = pv; rsum += pv;
    }
#pragma unroll
    for (int r = 0; r < 16; ++r) {
      const float pv = exp2f((s1[r] - m_run) * L2E); s1[r] = pv; rsum += pv;
    }
    rsum += __shfl_xor(rsum, 32);
    l_run += rsum;

    // ---- pack P, exchange m-quads with lane^32, PV: O^T += V^T * P ----
    const char* Vp = smem + 32768;
#pragma unroll
    for (int ks = 0; ks < 2; ++ks) {  // s0: m 0..31
      const int ok = 8 * ks + 4 * h;
      const int os = 8 * ks + 4 * (1 - h);
      const unsigned uA = pack2(s0[ok], s0[ok + 1]);
      const unsigned uB = pack2(s0[ok + 2], s0[ok + 3]);
      const unsigned vA = pack2(s0[os], s0[os + 1]);
      const unsigned vB = pack2(s0[os + 2], s0[os + 3]);
      const unsigned xA = (unsigned)__shfl_xor((int)vA, 32);
      const unsigned xB = (unsigned)__shfl_xor((int)vB, 32);
      u32x4 fu;
      if (h == 0) { fu[0] = uA; fu[1] = uB; fu[2] = xA; fu[3] = xB; }
      else        { fu[0] = xA; fu[1] = xB; fu[2] = uA; fu[3] = uB; }
      const short8 pb = __builtin_bit_cast(short8, fu);
      const int mb = ks * 32 + 16 * h;
      __builtin_amdgcn_s_setprio(1);
#pragma unroll
      for (int cf = 0; cf < 8; ++cf) {
        const int c = cf * 32 + l31;
        const short8 va =
            *(const short8*)(Vp + c * 128 + (mb ^ ((c & 7) << 4)));
        o[cf] = __builtin_amdgcn_mfma_f32_32x32x16_bf16(va, pb, o[cf], 0, 0, 0);
      }
      __builtin_amdgcn_s_setprio(0);
    }
#pragma unroll
    for (int ks = 0; ks < 2; ++ks) {  // s1: m 32..63
      const int ok = 8 * ks + 4 * h;
      const int os = 8 * ks + 4 * (1 - h);
      const unsigned uA = pack2(s1[ok], s1[ok + 1]);
      const unsigned uB = pack2(s1[ok + 2], s1[ok + 3]);
      const unsigned vA = pack2(s1[os], s1[os + 1]);
      const unsigned vB = pack2(s1[os + 2], s1[os + 3]);
      const unsigned xA = (unsigned)__shfl_xor((int)vA, 32);
      const unsigned xB = (unsigned)__shfl_xor((int)vB, 32);
      u32x4 fu;
      if (h == 0) { fu[0] = uA; fu[1] = uB; fu[2] = xA; fu[3] = xB; }
      else        { fu[0] = xA; fu[1] = xB; fu[2] = uA; fu[3] = uB; }
      const short8 pb = __builtin_bit_cast(short8, fu);
      const int mb = 64 + ks * 32 + 16 * h;
      __builtin_amdgcn_s_setprio(1);
#pragma unroll
      for (int cf = 0; cf < 8; ++cf) {
        const int c = cf * 32 + l31;
        const short8 va =
            *(const short8*)(Vp + c * 128 + (mb ^ ((c & 7) << 4)));
        o[cf] = __builtin_amdgcn_mfma_f32_32x32x16_bf16(va, pb, o[cf], 0, 0, 0);
      }
      __builtin_amdgcn_s_setprio(0);
    }
    __syncthreads();  // all waves done reading this tile's LDS
    if (t < T - 1) {
      STAGE(tBase + t + 1);
      __syncthreads();  // compiler drains vmcnt(0) -> tile ready
    }
  }
#undef STAGE

  // ---- epilogue ----
  if (SPLIT) {
    float* Od = OH + ((size_t)(half * 8 + b)) * NC * NNN;
#pragma unroll
    for (int cf = 0; cf < 8; ++cf)
#pragma unroll
      for (int r = 0; r < 16; ++r) {
        const int c = cf * 32 + (r & 3) + 8 * (r >> 2) + 4 * h;
        Od[(size_t)c * NNN + n0w + l31] = o[cf][r];
      }
    if (h == 0) {
      const size_t si = (size_t)(half * 8 + b) * NNN + n0w + l31;
      mS[si] = m_run;
      lS[si] = l_run;
    }
  } else {
    const float sc = gamma[0] / l_run;
#pragma unroll
    for (int cf = 0; cf < 8; ++cf)
#pragma unroll
      for (int r = 0; r < 16; ++r) {
        const int c = cf * 32 + (r & 3) + 8 * (r >> 2) + 4 * h;
        const size_t gi = ((size_t)(b * NC + c)) * NNN + n0w + l31;
        out[gi] = o[cf][r] * sc + x[gi];
      }
  }
}

// Flash merge of the two key-halves: out = gamma*(O0*w0+O1*w1)/(l0*w0+l1*w1)+x
__global__ __launch_bounds__(256) void combine_kernel(
    const float* __restrict__ x, const float* __restrict__ OH,
    const float* __restrict__ mS, const float* __restrict__ lS,
    const float* __restrict__ gamma, float* __restrict__ out) {
  const size_t qi = (size_t)blockIdx.x * 256 + threadIdx.x;  // 2M quads
  const int n4 = (int)(qi & 1023) * 4;
  const int c = (int)((qi >> 10) & 255);
  const int b = (int)(qi >> 18);
  const size_t si = (size_t)b * NNN + n4;
  const f32x4 m0 = *(const f32x4*)(mS + si);
  const f32x4 m1 = *(const f32x4*)(mS + (size_t)8 * NNN + si);
  const f32x4 l0 = *(const f32x4*)(lS + si);
  const f32x4 l1 = *(const f32x4*)(lS + (size_t)8 * NNN + si);
  const size_t oi = ((size_t)(b * NC + c)) * NNN + n4;
  const f32x4 O0 = *(const f32x4*)(OH + oi);
  const f32x4 O1 = *(const f32x4*)(OH + (size_t)8 * NC * NNN + oi);
  const f32x4 xv = *(const f32x4*)(x + oi);
  const float gam = gamma[0];
  f32x4 r;
#pragma unroll
  for (int j = 0; j < 4; ++j) {
    const float m = fmaxf(m0[j], m1[j]);
    const float w0 = exp2f((m0[j] - m) * L2E);
    const float w1 = exp2f((m1[j] - m) * L2E);
    r[j] = gam * (O0[j] * w0 + O1[j] * w1) / (l0[j] * w0 + l1[j] * w1) + xv[j];
  }
  *(f32x4*)(out + oi) = r;
}

extern "C" void kernel_launch(void* const* d_in, const int* in_sizes, int n_in,
                              void* d_out, int out_size, void* d_ws,
                              size_t ws_size, hipStream_t stream) {
  const float* x = (const float*)d_in[0];
  const float* gamma = (const float*)d_in[1];
  float* out = (float*)d_out;

  ushort* fTs = (ushort*)d_ws;                          // 16.78 MB
  ushort* fVs = fTs + (size_t)NB * NNN * NC;            // 16.78 MB
  float* OH = (float*)(fVs + (size_t)NB * NNN * NC);    // 67.11 MB
  float* mS = OH + (size_t)2 * NB * NC * NNN;           // 0.26 MB
  float* lS = mS + (size_t)2 * NB * NNN;                // 0.26 MB
  const size_t need = (size_t)2 * NB * NNN * NC * 2 +
                      (size_t)2 * NB * NC * NNN * 4 +
                      (size_t)4 * NB * NNN * 4;

  dim3 pg(NNN / 32, NC / 32, NB);
  dim3 pb(32, 8, 1);
  prep_T<<<pg, pb, 0, stream>>>(x, fTs);
  prep_V<<<dim3(4096), dim3(256), 0, stream>>>(x, fVs);

  if (ws_size >= need) {
    attn_kernel<1><<<dim3(512), dim3(256), 0, stream>>>(x, fTs, fVs, gamma,
                                                        out, OH, mS, lS);
    combine_kernel<<<dim3(8192), dim3(256), 0, stream>>>(x, OH, mS, lS, gamma,
                                                         out);
  } else {
    attn_kernel<0><<<dim3(256), dim3(256), 0, stream>>>(x, fTs, fVs, gamma,
                                                        out, OH, mS, lS);
  }
}

// Round 7
// 372.541 us; speedup vs baseline: 1.8248x; 1.8248x over previous
//
#include <hip/hip_runtime.h>
#include <hip/hip_bf16.h>

typedef __attribute__((ext_vector_type(8))) short short8;
typedef __attribute__((ext_vector_type(4))) float f32x4;
typedef __attribute__((ext_vector_type(16))) float f32x16;
typedef __attribute__((ext_vector_type(4))) unsigned int u32x4;

#define NB 8
#define NC 256
#define NNN 4096
#define L2E 1.44269504088896f

__device__ __forceinline__ ushort f2bf(float f) {
  __hip_bfloat16 h = __float2bfloat16(f);
  return *reinterpret_cast<ushort*>(&h);
}
__device__ __forceinline__ unsigned pack2(float a, float b) {
  return (unsigned)f2bf(a) | ((unsigned)f2bf(b) << 16);
}
__device__ __forceinline__ void gload16(const void* g, void* l) {
  __builtin_amdgcn_global_load_lds(
      (const __attribute__((address_space(1))) void*)g,
      (__attribute__((address_space(3))) void*)l, 16, 0, 0);
}

// fTs[b][n][c ^ ((n&7)<<3)] = bf16(x[b][c][n])   (chunk-swizzled rows, 512B)
__global__ __launch_bounds__(256) void prep_T(const float* __restrict__ x,
                                              ushort* __restrict__ fTs) {
  __shared__ float tile[32][33];
  const int tx = threadIdx.x, ty = threadIdx.y;
  const int n0 = blockIdx.x * 32, c0 = blockIdx.y * 32, b = blockIdx.z;
#pragma unroll
  for (int k = 0; k < 4; ++k) {
    tile[ty + 8 * k][tx] =
        x[((size_t)(b * NC + c0 + ty + 8 * k)) * NNN + n0 + tx];
  }
  __syncthreads();
#pragma unroll
  for (int k = 0; k < 4; ++k) {
    const int n = n0 + ty + 8 * k;
    const int c = c0 + tx;
    fTs[(size_t)(b * NNN + n) * NC + (c ^ ((n & 7) << 3))] =
        f2bf(tile[tx][ty + 8 * k]);
  }
}

// fVs[b][c][64t + (mm ^ ((c&7)<<3))] = bf16(x[b][c][64t+mm])
__global__ __launch_bounds__(256) void prep_V(const float* __restrict__ x,
                                              ushort* __restrict__ fVs) {
  const size_t ci = (size_t)blockIdx.x * 256 + threadIdx.x;  // 1M chunks
  const int p = (int)(ci & 511);
  const int c = (int)((ci >> 9) & 255);
  const int b = (int)(ci >> 17);
  const int lp = (p & ~7) | ((p & 7) ^ (c & 7));  // logical chunk
  const float* src = x + ((size_t)(b * NC + c)) * NNN + lp * 8;
  f32x4 a0 = *(const f32x4*)src;
  f32x4 a1 = *(const f32x4*)(src + 4);
  short8 w;
  w[0] = (short)f2bf(a0[0]); w[1] = (short)f2bf(a0[1]);
  w[2] = (short)f2bf(a0[2]); w[3] = (short)f2bf(a0[3]);
  w[4] = (short)f2bf(a1[0]); w[5] = (short)f2bf(a1[1]);
  w[6] = (short)f2bf(a1[2]); w[7] = (short)f2bf(a1[3]);
  *(short8*)(fVs + ((size_t)(b * NC + c)) * NNN + p * 8) = w;
}

// Flash attention, 32x32x16 MFMA, swapped QK^T, O^T (n per-lane) accumulation.
// 512 threads = 8 waves = 4 n-groups x 2 INDEPENDENT m-halves (no mid-tile
// exchange; exact weighted flash-merge in epilogue). Grid 256, 2 waves/SIMD.
// LDS: dbuf 2x{K 32KB + V 32KB} = 128KB + 1KB stats.
__global__ __launch_bounds__(512, 2) void attn_kernel(
    const float* __restrict__ x, const ushort* __restrict__ fTs,
    const ushort* __restrict__ fVs, const float* __restrict__ gamma,
    float* __restrict__ out) {
  __shared__ __align__(16) char smem[133120];
  float* statsM = (float*)(smem + 131072);        // [4 groups][32 cols]
  float* statsL = (float*)(smem + 131072 + 512);  // [4 groups][32 cols]

  const int tid = threadIdx.x;
  const int w8 = tid >> 6;  // wave 0..7
  const int g = w8 >> 1;    // n-group 0..3
  const int mh = w8 & 1;    // m-half 0..1 (independent stats)
  const int l = tid & 63;
  const int l31 = l & 31;
  const int h = l >> 5;
  const int bid = blockIdx.x;
  const int b = bid & 7;             // batch -> XCD
  const int nt = bid >> 3;           // n-tile (128 query rows)
  const int n0w = nt * 128 + g * 32; // this wave's 32 query cols

  const char* fTb = (const char*)(fTs + (size_t)b * NNN * NC);
  const char* fVb = (const char*)(fVs + (size_t)b * NNN * NC);

  // Q fragments (B operand): col n = l31 -> row n0w+l31; k = kc*16+8h+j
  short8 q[16];
  {
    const char* qrow = fTb + (size_t)(n0w + l31) * 512;
    const int sw = (l31 & 7) << 4;
#pragma unroll
    for (int kc = 0; kc < 16; ++kc)
      q[kc] = *(const short8*)(qrow + ((kc * 32 + 16 * h) ^ sw));
  }

  // O^T accumulator: rows c = cf*32 + (r&3)+8*(r>>2)+4h, cols n = l31
  f32x16 o[8];
#pragma unroll
  for (int cf = 0; cf < 8; ++cf)
#pragma unroll
    for (int r = 0; r < 16; ++r) o[cf][r] = 0.f;
  float m_run = -3.0e38f, l_run = 0.f;

  // DMA staging (512 threads): K rows = LDS rows linear; V per R5 layout
  const char* kSrc = fTb + tid * 16;
  const char* vSrc = fVb + (size_t)(l >> 3) * 8192 + (l & 7) * 16;

#define STAGE(tt, dst)                                                        \
  {                                                                           \
    const size_t kOff = (size_t)(tt) * 32768;                                 \
    const size_t vOff = (size_t)(tt) * 128;                                   \
    _Pragma("unroll") for (int i = 0; i < 4; ++i)                             \
        gload16(kSrc + kOff + i * 8192, (dst) + w8 * 1024 + i * 8192);        \
    _Pragma("unroll") for (int i = 0; i < 4; ++i)                             \
        gload16(vSrc + vOff + (size_t)(i * 8 + w8) * 65536,                   \
                (dst) + 32768 + w8 * 1024 + i * 8192);                        \
  }

  STAGE(0, smem);
  __syncthreads();

  const int krow = mh * 32 + l31;
  const int ksw = (l31 & 7) << 4;

  for (int t = 0; t < 64; ++t) {
    char* bufC = smem + (t & 1) * 65536;
    if (t < 63) {  // issue next tile's DMA; drains at this tile's end barrier
      char* bufN = smem + ((t + 1) & 1) * 65536;
      STAGE(t + 1, bufN);
    }

    // ---- S^T = K(m-half) * Q^T : two independent 8-chains ----
    f32x16 sa, sb;
#pragma unroll
    for (int r = 0; r < 16; ++r) { sa[r] = 0.f; sb[r] = 0.f; }
    __builtin_amdgcn_s_setprio(1);
#pragma unroll
    for (int kc = 0; kc < 8; ++kc) {
      const int b0 = (kc * 32 + 16 * h) ^ ksw;
      const int b1 = ((kc + 8) * 32 + 16 * h) ^ ksw;
      short8 ka = *(const short8*)(bufC + krow * 512 + b0);
      short8 kb = *(const short8*)(bufC + krow * 512 + b1);
      sa = __builtin_amdgcn_mfma_f32_32x32x16_bf16(ka, q[kc], sa, 0, 0, 0);
      sb = __builtin_amdgcn_mfma_f32_32x32x16_bf16(kb, q[kc + 8], sb, 0, 0, 0);
    }
    __builtin_amdgcn_s_setprio(0);
    f32x16 s;
#pragma unroll
    for (int r = 0; r < 16; ++r) s[r] = sa[r] + sb[r];

    // ---- independent online softmax; lane owns col n = l31 ----
    float tm = s[0];
#pragma unroll
    for (int r = 1; r < 16; ++r) tm = fmaxf(tm, s[r]);
    tm = fmaxf(tm, __shfl_xor(tm, 32));

    if (__any(tm > m_run + 8.f)) {  // T13 defer-max
      const float mnew = fmaxf(m_run, tm);
      const float alpha = exp2f((m_run - mnew) * L2E);
      m_run = mnew;
      l_run *= alpha;
#pragma unroll
      for (int cf = 0; cf < 8; ++cf)
#pragma unroll
        for (int r = 0; r < 16; ++r) o[cf][r] *= alpha;  // lane-local
    }

    float rsum = 0.f;
#pragma unroll
    for (int r = 0; r < 16; ++r) {
      const float pv = exp2f((s[r] - m_run) * L2E);
      s[r] = pv;
      rsum += pv;
    }
    rsum += __shfl_xor(rsum, 32);
    l_run += rsum;

    // ---- pack P, exchange m-quads with lane^32, PV: O^T += V^T * P ----
    const char* Vp = bufC + 32768;
#pragma unroll
    for (int ks = 0; ks < 2; ++ks) {
      const int ok = 8 * ks + 4 * h;
      const int os = 8 * ks + 4 * (1 - h);
      const unsigned uA = pack2(s[ok], s[ok + 1]);
      const unsigned uB = pack2(s[ok + 2], s[ok + 3]);
      const unsigned vA = pack2(s[os], s[os + 1]);
      const unsigned vB = pack2(s[os + 2], s[os + 3]);
      const unsigned xA = (unsigned)__shfl_xor((int)vA, 32);
      const unsigned xB = (unsigned)__shfl_xor((int)vB, 32);
      u32x4 fu;
      if (h == 0) { fu[0] = uA; fu[1] = uB; fu[2] = xA; fu[3] = xB; }
      else        { fu[0] = xA; fu[1] = xB; fu[2] = uA; fu[3] = uB; }
      const short8 pb = __builtin_bit_cast(short8, fu);
      const int mb = mh * 64 + ks * 32 + 16 * h;
      __builtin_amdgcn_s_setprio(1);
#pragma unroll
      for (int cf = 0; cf < 8; ++cf) {
        const int c = cf * 32 + l31;
        const short8 va =
            *(const short8*)(Vp + c * 128 + (mb ^ ((c & 7) << 4)));
        o[cf] = __builtin_amdgcn_mfma_f32_32x32x16_bf16(va, pb, o[cf], 0, 0, 0);
      }
      __builtin_amdgcn_s_setprio(0);
    }
    __syncthreads();  // LDS reads done + next tile's DMA drained
  }
#undef STAGE

  // ---- epilogue: exact flash merge of the two independent m-halves ----
  if (mh == 1) {
    statsM[g * 32 + l31] = m_run;  // h=0/h=1 write identical values
    statsL[g * 32 + l31] = l_run;
    float* Og = (float*)(smem + g * 32768);
#pragma unroll
    for (int cf = 0; cf < 8; ++cf)
#pragma unroll
      for (int r = 0; r < 16; ++r) {
        const int c = cf * 32 + (r & 3) + 8 * (r >> 2) + 4 * h;
        Og[c * 32 + l31] = o[cf][r];
      }
  }
  __syncthreads();
  if (mh == 0) {
    const float m1 = statsM[g * 32 + l31];
    const float l1 = statsL[g * 32 + l31];
    const float m = fmaxf(m_run, m1);
    const float w0 = exp2f((m_run - m) * L2E);
    const float w1 = exp2f((m1 - m) * L2E);
    const float sc = gamma[0] / (l_run * w0 + l1 * w1);
    const float* Og = (const float*)(smem + g * 32768);
#pragma unroll
    for (int cf = 0; cf < 8; ++cf)
#pragma unroll
      for (int r = 0; r < 16; ++r) {
        const int c = cf * 32 + (r & 3) + 8 * (r >> 2) + 4 * h;
        const float val = (o[cf][r] * w0 + Og[c * 32 + l31] * w1) * sc;
        const size_t gi = ((size_t)(b * NC + c)) * NNN + n0w + l31;
        out[gi] = val + x[gi];
      }
  }
}

extern "C" void kernel_launch(void* const* d_in, const int* in_sizes, int n_in,
                              void* d_out, int out_size, void* d_ws,
                              size_t ws_size, hipStream_t stream) {
  const float* x = (const float*)d_in[0];
  const float* gamma = (const float*)d_in[1];
  float* out = (float*)d_out;
  ushort* fTs = (ushort*)d_ws;                          // 16.78 MB
  ushort* fVs = fTs + (size_t)NB * NNN * NC;            // 16.78 MB

  dim3 pg(NNN / 32, NC / 32, NB);
  dim3 pb(32, 8, 1);
  prep_T<<<pg, pb, 0, stream>>>(x, fTs);
  prep_V<<<dim3(4096), dim3(256), 0, stream>>>(x, fVs);

  attn_kernel<<<dim3(256), dim3(512), 0, stream>>>(x, fTs, fVs, gamma, out);
}